// Round 1
// 309.285 us; speedup vs baseline: 1.0686x; 1.0686x over previous
//
#include <hip/hip_runtime.h>

#define TSEQ   512
#define BATCH  4096
#define MROWS  16

typedef short bf16x8 __attribute__((ext_vector_type(8)));
typedef short bf16x4 __attribute__((ext_vector_type(4)));
typedef float f32x4  __attribute__((ext_vector_type(4)));
typedef float f32x2  __attribute__((ext_vector_type(2)));
typedef unsigned int u32x2 __attribute__((ext_vector_type(2)));

#define NL2E  (-1.44269504f)
#define P2L2E (2.88539008f)

__device__ __forceinline__ unsigned short f2bf(float f) {
    unsigned int u = __builtin_bit_cast(unsigned int, f);
    return (unsigned short)((u + 0x8000u) >> 16);
}

// Gate math for TWO cells at once, vectorized as f32x2 so clang emits
// v_pk_{add,mul,fma}_f32 (full-rate packed fp32 on gfx950). Transcendentals
// stay scalar (no packed trans on CDNA) but their results are fresh defs, so
// building the pairs is free in regalloc.
// a,b pre-scaled accs: exp2(a0)=e^-i, exp2(a1)=e^-f, exp2(a2)=e^{2g},
// exp2(a3)=e^-o. C = cell-state pair scaled by 2*log2e.
__device__ __forceinline__ f32x2 cellupd2(const f32x4 a, const f32x4 b, f32x2& C) {
    f32x2 ei = {__builtin_amdgcn_exp2f(a[0]), __builtin_amdgcn_exp2f(b[0])};
    f32x2 ef = {__builtin_amdgcn_exp2f(a[1]), __builtin_amdgcn_exp2f(b[1])};
    f32x2 eg = {__builtin_amdgcn_exp2f(a[2]), __builtin_amdgcn_exp2f(b[2])};
    f32x2 eo = {__builtin_amdgcn_exp2f(a[3]), __builtin_amdgcn_exp2f(b[3])};
    f32x2 A  = 1.f + ei;                       // pk_add
    f32x2 G1 = eg + 1.f;                       // pk_add
    f32x2 F  = 1.f + ef;                       // pk_add
    f32x2 t  = A * G1;                         // pk_mul
    f32x2 G2 = eg * P2L2E + (NL2E * 2.f);      // pk_fma
    f32x2 num = C * t + G2 * F;                // pk_mul + pk_fma
    f32x2 den = t * F;                         // pk_mul
    f32x2 r  = {__builtin_amdgcn_rcpf(den.x), __builtin_amdgcn_rcpf(den.y)};
    f32x2 Cn = num * r;                        // pk_mul
    Cn.x = fminf(Cn.x, 126.f);
    Cn.y = fminf(Cn.y, 126.f);
    C = Cn;
    f32x2 ec = {__builtin_amdgcn_exp2f(Cn.x), __builtin_amdgcn_exp2f(Cn.y)};
    f32x2 B  = 1.f + eo;                       // pk_add
    f32x2 hn = ec - 1.f;                       // pk_add
    f32x2 hd = B * (ec + 1.f);                 // pk_add + pk_mul
    f32x2 rr = {__builtin_amdgcn_rcpf(hd.x), __builtin_amdgcn_rcpf(hd.y)};
    return hn * rr;                            // pk_mul
}

// ring/h2s rows: 64 bf16 = 128B, XOR swizzle byte ^= ((row&7)<<4) on write+read.
// xq: 64 slot-rows x 16 cols x 8 bf16 (16B frag), swizzle byte ^= ((t64&7)<<4).

__global__ __launch_bounds__(512, 2) void lstm2_kernel(
    const float* __restrict__ x,
    const float* __restrict__ Wih0, const float* __restrict__ Whh0,
    const float* __restrict__ bih0, const float* __restrict__ bhh0,
    const float* __restrict__ Wih1, const float* __restrict__ Whh1,
    const float* __restrict__ bih1, const float* __restrict__ bhh1,
    const float* __restrict__ Wc1,  const float* __restrict__ bc1,
    const float* __restrict__ Wc2,  const float* __restrict__ bc2,
    float* __restrict__ out)
{
    __shared__ __align__(16) unsigned short ring[2][MROWS * 64];
    __shared__ __align__(16) unsigned short h2s[2][MROWS * 64];
    __shared__ __align__(16) unsigned short xq[64][128];   // 16 KB
    __shared__ float h2f[MROWS][65];
    __shared__ float hid[MROWS][33];

    const int tid  = threadIdx.x;
    const int wv   = tid >> 6;        // 0..7
    const int lane = tid & 63;
    const int col  = lane & 15;       // batch index (B-operand col / A-row)
    const int lg   = lane >> 4;       // k-group
    const int b0   = blockIdx.x * MROWS;
    const int sw   = (col & 7) << 4;

    for (int i = tid; i < 1024; i += 512) {
        ((unsigned int*)ring)[i] = 0u;
        ((unsigned int*)h2s)[i]  = 0u;
    }

    // ---- x chunk 0 convert (into xq rows 0..31) + chunk 1 prefetch ----
    const int xrow = tid >> 5;        // 0..15
    const int xt   = tid & 31;        // 0..31 (chunk-local timestep)
    const float* xb = x + ((size_t)(b0 + xrow) * TSEQ + xt) * 3;
    float xr0 = xb[0], xr1 = xb[1], xr2 = xb[2];
    {
        bf16x8 xf = {(short)f2bf(xr0),(short)f2bf(xr1),(short)f2bf(xr2),0,0,0,0,0};
        *(bf16x8*)((char*)xq + (xt << 8) + ((xrow << 4) ^ ((xt & 7) << 4))) = xf;
    }
    xr0 = xb[96]; xr1 = xb[97]; xr2 = xb[98];
    __syncthreads();

    const int rd0 = (col * 128 +      lg * 16) ^ sw;
    const int rd1 = (col * 128 + 64 + lg * 16) ^ sw;

#define FLUSH(S) do { \
    if (((S) & 31) == 16 && (S) < 480) { \
        const int c1_ = ((S) >> 5) + 1; \
        const int t64_ = ((c1_ & 1) << 5) + xt; \
        bf16x8 xf_ = {(short)f2bf(xr0),(short)f2bf(xr1),(short)f2bf(xr2),0,0,0,0,0}; \
        *(bf16x8*)((char*)xq + (t64_ << 8) + ((xrow << 4) ^ ((xt & 7) << 4))) = xf_; \
        if (c1_ < 15) { const float* p_ = xb + (c1_ + 1) * 96; xr0 = p_[0]; xr1 = p_[1]; xr2 = p_[2]; } \
    } \
} while(0)

    if (wv < 4) {
        // ========== L1 waves: 4 tiles each; lane owns units u=16lg+4wv+{0..3} ==========
        const int wq = wv;
        const int ga = col & 3;
        const float sca = (ga == 2) ? P2L2E : NL2E;
        bf16x8 Wf[4][3];
        f32x4 bia4[4];
#pragma unroll
        for (int tt = 0; tt < 4; ++tt) {
            const int n = ga * 64 + 16 * (col >> 2) + 4 * wq + tt;
#pragma unroll
            for (int f = 0; f < 3; ++f)
#pragma unroll
                for (int i = 0; i < 8; ++i) {
                    const int k = f * 32 + lg * 8 + i;
                    float v = 0.f;
                    if (k < 64)      v = Whh0[n * 64 + k];
                    else if (k < 67) v = Wih0[n * 3 + (k - 64)];
                    Wf[tt][f][i] = (short)f2bf(sca * v);
                }
#pragma unroll
            for (int r = 0; r < 4; ++r) {
                const int nb = r * 64 + 16 * lg + 4 * wq + tt;
                bia4[tt][r] = ((r == 2) ? P2L2E : NL2E) * (bih0[nb] + bhh0[nb]);
            }
        }
        const int hw = (col * 128 + 32 * lg + 8 * wq) ^ sw;
        f32x2 C01 = {0.f, 0.f};
        f32x2 C23 = {0.f, 0.f};

#define L1B(RI, WI, S) do { \
        const char* rb_ = (const char*)ring[RI]; \
        bf16x8 v0_ = *(const bf16x8*)(rb_ + rd0); \
        bf16x8 v1_ = *(const bf16x8*)(rb_ + rd1); \
        bf16x8 v2_ = {0,0,0,0,0,0,0,0}; \
        if (lg == 0) \
            v2_ = *(const bf16x8*)((const char*)xq + ((((S)&63)) << 8) + ((col << 4) ^ (((S)&7) << 4))); \
        f32x4 a0_ = __builtin_amdgcn_mfma_f32_16x16x32_bf16(Wf[0][0], v0_, bia4[0],0,0,0); \
        f32x4 a1_ = __builtin_amdgcn_mfma_f32_16x16x32_bf16(Wf[1][0], v0_, bia4[1],0,0,0); \
        f32x4 a2_ = __builtin_amdgcn_mfma_f32_16x16x32_bf16(Wf[2][0], v0_, bia4[2],0,0,0); \
        f32x4 a3_ = __builtin_amdgcn_mfma_f32_16x16x32_bf16(Wf[3][0], v0_, bia4[3],0,0,0); \
        a0_ = __builtin_amdgcn_mfma_f32_16x16x32_bf16(Wf[0][1], v1_, a0_,0,0,0); \
        a1_ = __builtin_amdgcn_mfma_f32_16x16x32_bf16(Wf[1][1], v1_, a1_,0,0,0); \
        a2_ = __builtin_amdgcn_mfma_f32_16x16x32_bf16(Wf[2][1], v1_, a2_,0,0,0); \
        a3_ = __builtin_amdgcn_mfma_f32_16x16x32_bf16(Wf[3][1], v1_, a3_,0,0,0); \
        a0_ = __builtin_amdgcn_mfma_f32_16x16x32_bf16(Wf[0][2], v2_, a0_,0,0,0); \
        a1_ = __builtin_amdgcn_mfma_f32_16x16x32_bf16(Wf[1][2], v2_, a1_,0,0,0); \
        a2_ = __builtin_amdgcn_mfma_f32_16x16x32_bf16(Wf[2][2], v2_, a2_,0,0,0); \
        a3_ = __builtin_amdgcn_mfma_f32_16x16x32_bf16(Wf[3][2], v2_, a3_,0,0,0); \
        f32x2 h01_ = cellupd2(a0_, a1_, C01); \
        f32x2 h23_ = cellupd2(a2_, a3_, C23); \
        unsigned int p0_, p1_; \
        asm("v_cvt_pk_bf16_f32 %0, %1, %2" : "=v"(p0_) : "v"(h01_.x), "v"(h01_.y)); \
        asm("v_cvt_pk_bf16_f32 %0, %1, %2" : "=v"(p1_) : "v"(h23_.x), "v"(h23_.y)); \
        u32x2 pk_ = {p0_, p1_}; \
        *(u32x2*)((char*)ring[WI] + hw) = pk_; \
    } while(0)

        L1B(1, 0, 0);
        __syncthreads();                           // end slot 0
#pragma unroll 1
        for (int m = 0; m < 255; ++m) {
            const int s1 = 2 * m + 1;
            L1B(0, 1, s1);
            __syncthreads();                       // end odd slot
            L1B(1, 0, s1 + 1);
            FLUSH(s1 + 1);
            __syncthreads();                       // end even slot
        }
        L1B(0, 1, 511);
        __syncthreads();                           // end slot 511
        __syncthreads();                           // slot 512 idle
#undef L1B
    } else {
        // ========== L2 waves: lag 1; K = [h1(64) | h2(64)] ==========
        const int wq = wv - 4;
        const int ga = col & 3;
        const float sca = (ga == 2) ? P2L2E : NL2E;
        bf16x8 Wf[4][4];
        f32x4 bia4[4];
#pragma unroll
        for (int tt = 0; tt < 4; ++tt) {
            const int n = ga * 64 + 16 * (col >> 2) + 4 * wq + tt;
#pragma unroll
            for (int f = 0; f < 4; ++f)
#pragma unroll
                for (int i = 0; i < 8; ++i) {
                    const int k = f * 32 + lg * 8 + i;
                    const float v = (k < 64) ? Wih1[n * 64 + k] : Whh1[n * 64 + (k - 64)];
                    Wf[tt][f][i] = (short)f2bf(sca * v);
                }
#pragma unroll
            for (int r = 0; r < 4; ++r) {
                const int nb = r * 64 + 16 * lg + 4 * wq + tt;
                bia4[tt][r] = ((r == 2) ? P2L2E : NL2E) * (bih1[nb] + bhh1[nb]);
            }
        }
        const int hw2 = (col * 128 + 32 * lg + 8 * wq) ^ sw;
        f32x2 C01 = {0.f, 0.f};
        f32x2 C23 = {0.f, 0.f};
        f32x2 hv01 = {0.f, 0.f};
        f32x2 hv23 = {0.f, 0.f};

#define L2B(RB, HR) do { \
        const char* rb_ = (const char*)ring[RB]; \
        const char* hp_ = (const char*)h2s[HR]; \
        bf16x8 v0_ = *(const bf16x8*)(rb_ + rd0); \
        bf16x8 v1_ = *(const bf16x8*)(rb_ + rd1); \
        bf16x8 v2_ = *(const bf16x8*)(hp_ + rd0); \
        bf16x8 v3_ = *(const bf16x8*)(hp_ + rd1); \
        f32x4 a0_ = __builtin_amdgcn_mfma_f32_16x16x32_bf16(Wf[0][0], v0_, bia4[0],0,0,0); \
        f32x4 a1_ = __builtin_amdgcn_mfma_f32_16x16x32_bf16(Wf[1][0], v0_, bia4[1],0,0,0); \
        f32x4 a2_ = __builtin_amdgcn_mfma_f32_16x16x32_bf16(Wf[2][0], v0_, bia4[2],0,0,0); \
        f32x4 a3_ = __builtin_amdgcn_mfma_f32_16x16x32_bf16(Wf[3][0], v0_, bia4[3],0,0,0); \
        a0_ = __builtin_amdgcn_mfma_f32_16x16x32_bf16(Wf[0][1], v1_, a0_,0,0,0); \
        a1_ = __builtin_amdgcn_mfma_f32_16x16x32_bf16(Wf[1][1], v1_, a1_,0,0,0); \
        a2_ = __builtin_amdgcn_mfma_f32_16x16x32_bf16(Wf[2][1], v1_, a2_,0,0,0); \
        a3_ = __builtin_amdgcn_mfma_f32_16x16x32_bf16(Wf[3][1], v1_, a3_,0,0,0); \
        a0_ = __builtin_amdgcn_mfma_f32_16x16x32_bf16(Wf[0][2], v2_, a0_,0,0,0); \
        a1_ = __builtin_amdgcn_mfma_f32_16x16x32_bf16(Wf[1][2], v2_, a1_,0,0,0); \
        a2_ = __builtin_amdgcn_mfma_f32_16x16x32_bf16(Wf[2][2], v2_, a2_,0,0,0); \
        a3_ = __builtin_amdgcn_mfma_f32_16x16x32_bf16(Wf[3][2], v2_, a3_,0,0,0); \
        a0_ = __builtin_amdgcn_mfma_f32_16x16x32_bf16(Wf[0][3], v3_, a0_,0,0,0); \
        a1_ = __builtin_amdgcn_mfma_f32_16x16x32_bf16(Wf[1][3], v3_, a1_,0,0,0); \
        a2_ = __builtin_amdgcn_mfma_f32_16x16x32_bf16(Wf[2][3], v3_, a2_,0,0,0); \
        a3_ = __builtin_amdgcn_mfma_f32_16x16x32_bf16(Wf[3][3], v3_, a3_,0,0,0); \
        hv01 = cellupd2(a0_, a1_, C01); \
        hv23 = cellupd2(a2_, a3_, C23); \
        unsigned int p0_, p1_; \
        asm("v_cvt_pk_bf16_f32 %0, %1, %2" : "=v"(p0_) : "v"(hv01.x), "v"(hv01.y)); \
        asm("v_cvt_pk_bf16_f32 %0, %1, %2" : "=v"(p1_) : "v"(hv23.x), "v"(hv23.y)); \
        u32x2 pk_ = {p0_, p1_}; \
        *(u32x2*)((char*)h2s[RB] + hw2) = pk_; \
    } while(0)

        __syncthreads();                           // slot 0 idle
#pragma unroll 1
        for (int m = 0; m < 255; ++m) {
            L2B(0, 1);                             // slot 2m+1, t=2m
            __syncthreads();
            L2B(1, 0);                             // slot 2m+2, t=2m+1
            FLUSH(2 * m + 2);
            __syncthreads();
        }
        L2B(0, 1);                                 // slot 511, t=510
        __syncthreads();
        L2B(1, 0);                                 // slot 512, t=511
        __syncthreads();
#undef L2B
        const int ub = 16 * lg + 4 * wq;
        h2f[col][ub + 0] = hv01.x;
        h2f[col][ub + 1] = hv01.y;
        h2f[col][ub + 2] = hv23.x;
        h2f[col][ub + 3] = hv23.y;
    }
    __syncthreads();

    // ================= classifier head =================
    {
        const int b = tid & 15, j = tid >> 4;      // j 0..31 over 512 threads
        float s = bc1[j];
#pragma unroll 8
        for (int k = 0; k < 64; ++k) s += Wc1[j * 64 + k] * h2f[b][k];
        hid[b][j] = fmaxf(s, 0.f);
    }
    __syncthreads();
    if (tid < 16) {
        float s = bc2[0];
#pragma unroll 8
        for (int k = 0; k < 32; ++k) s += Wc2[k] * hid[tid][k];
        float e = __builtin_amdgcn_exp2f(NL2E * s);
        out[b0 + tid] = __builtin_amdgcn_rcpf(1.f + e);
    }
}

extern "C" void kernel_launch(void* const* d_in, const int* in_sizes, int n_in,
                              void* d_out, int out_size, void* d_ws, size_t ws_size,
                              hipStream_t stream) {
    lstm2_kernel<<<BATCH / MROWS, 512, 0, stream>>>(
        (const float*)d_in[0],
        (const float*)d_in[1], (const float*)d_in[2],
        (const float*)d_in[3], (const float*)d_in[4],
        (const float*)d_in[5], (const float*)d_in[6],
        (const float*)d_in[7], (const float*)d_in[8],
        (const float*)d_in[9], (const float*)d_in[10],
        (const float*)d_in[11], (const float*)d_in[12],
        (float*)d_out);
}

// Round 2
// 293.343 us; speedup vs baseline: 1.1266x; 1.0543x over previous
//
#include <hip/hip_runtime.h>

#define TSEQ   512
#define BATCH  4096
#define MROWS  16

typedef short bf16x8 __attribute__((ext_vector_type(8)));
typedef short bf16x4 __attribute__((ext_vector_type(4)));
typedef float f32x4  __attribute__((ext_vector_type(4)));
typedef float f32x2  __attribute__((ext_vector_type(2)));

#define NL2E  (-1.44269504f)
#define P2L2E (2.88539008f)

__device__ __forceinline__ unsigned short f2bf(float f) {
    unsigned int u = __builtin_bit_cast(unsigned int, f);
    return (unsigned short)((u + 0x8000u) >> 16);
}

// Gate math for TWO cells at once, vectorized as f32x2 so clang emits
// v_pk_{add,mul,fma}_f32. Transcendentals stay scalar (no packed trans).
// a,b pre-scaled accs: exp2(a0)=e^-i, exp2(a1)=e^-f, exp2(a2)=e^{2g},
// exp2(a3)=e^-o. C = cell-state pair scaled by 2*log2e.
__device__ __forceinline__ f32x2 cellupd2(const f32x4 a, const f32x4 b, f32x2& C) {
    f32x2 ei = {__builtin_amdgcn_exp2f(a[0]), __builtin_amdgcn_exp2f(b[0])};
    f32x2 ef = {__builtin_amdgcn_exp2f(a[1]), __builtin_amdgcn_exp2f(b[1])};
    f32x2 eg = {__builtin_amdgcn_exp2f(a[2]), __builtin_amdgcn_exp2f(b[2])};
    f32x2 eo = {__builtin_amdgcn_exp2f(a[3]), __builtin_amdgcn_exp2f(b[3])};
    f32x2 A  = 1.f + ei;
    f32x2 G1 = eg + 1.f;
    f32x2 F  = 1.f + ef;
    f32x2 t  = A * G1;
    f32x2 G2 = eg * P2L2E + (NL2E * 2.f);
    f32x2 num = C * t + G2 * F;
    f32x2 den = t * F;
    f32x2 r  = {__builtin_amdgcn_rcpf(den.x), __builtin_amdgcn_rcpf(den.y)};
    f32x2 Cn = num * r;
    Cn.x = fminf(Cn.x, 126.f);
    Cn.y = fminf(Cn.y, 126.f);
    C = Cn;
    f32x2 ec = {__builtin_amdgcn_exp2f(Cn.x), __builtin_amdgcn_exp2f(Cn.y)};
    f32x2 B  = 1.f + eo;
    f32x2 hn = ec - 1.f;
    f32x2 hd = B * (ec + 1.f);
    f32x2 rr = {__builtin_amdgcn_rcpf(hd.x), __builtin_amdgcn_rcpf(hd.y)};
    return hn * rr;
}

// ring/h2s rows: 64 bf16 = 128B, XOR swizzle byte ^= ((row&7)<<4) on write+read.
// xq: 64 slot-rows x 16 cols x 8 bf16 (16B frag), swizzle byte ^= ((t64&7)<<4).
// 16 waves: wv 0..7 = L1 (2 units/lane), wv 8..15 = L2 (lag 1).

__global__ __launch_bounds__(1024, 4) void lstm2_kernel(
    const float* __restrict__ x,
    const float* __restrict__ Wih0, const float* __restrict__ Whh0,
    const float* __restrict__ bih0, const float* __restrict__ bhh0,
    const float* __restrict__ Wih1, const float* __restrict__ Whh1,
    const float* __restrict__ bih1, const float* __restrict__ bhh1,
    const float* __restrict__ Wc1,  const float* __restrict__ bc1,
    const float* __restrict__ Wc2,  const float* __restrict__ bc2,
    float* __restrict__ out)
{
    __shared__ __align__(16) unsigned short ring[2][MROWS * 64];
    __shared__ __align__(16) unsigned short h2s[2][MROWS * 64];
    __shared__ __align__(16) unsigned short xq[64][128];   // 16 KB
    __shared__ float h2f[MROWS][65];
    __shared__ float hid[MROWS][33];

    const int tid  = threadIdx.x;
    const int wv   = tid >> 6;        // 0..15
    const int lane = tid & 63;
    const int col  = lane & 15;       // batch index (B-operand col / A-row)
    const int lg   = lane >> 4;       // k-group
    const int b0   = blockIdx.x * MROWS;
    const int sw   = (col & 7) << 4;

    // ring+h2s zero init: exactly 1024 u32 each pair
    ((unsigned int*)ring)[tid] = 0u;
    ((unsigned int*)h2s)[tid]  = 0u;

    // ---- x chunk 0 convert (into xq rows 0..31) + chunk 1 prefetch ----
    // staging owned by L1 threads (tid < 512), which span xrow 0..15 x xt 0..31
    const int xrow = (tid >> 5) & 15;
    const int xt   = tid & 31;        // chunk-local timestep
    const float* xb = x + ((size_t)(b0 + xrow) * TSEQ + xt) * 3;
    float xr0 = 0.f, xr1 = 0.f, xr2 = 0.f;
    if (tid < 512) {
        xr0 = xb[0]; xr1 = xb[1]; xr2 = xb[2];
        bf16x8 xf = {(short)f2bf(xr0),(short)f2bf(xr1),(short)f2bf(xr2),0,0,0,0,0};
        *(bf16x8*)((char*)xq + (xt << 8) + ((xrow << 4) ^ ((xt & 7) << 4))) = xf;
        xr0 = xb[96]; xr1 = xb[97]; xr2 = xb[98];
    }
    __syncthreads();

    const int rd0 = (col * 128 +      lg * 16) ^ sw;
    const int rd1 = (col * 128 + 64 + lg * 16) ^ sw;

#define FLUSH(S) do { \
    if (((S) & 31) == 16 && (S) < 480) { \
        const int c1_ = ((S) >> 5) + 1; \
        const int t64_ = ((c1_ & 1) << 5) + xt; \
        bf16x8 xf_ = {(short)f2bf(xr0),(short)f2bf(xr1),(short)f2bf(xr2),0,0,0,0,0}; \
        *(bf16x8*)((char*)xq + (t64_ << 8) + ((xrow << 4) ^ ((xt & 7) << 4))) = xf_; \
        if (c1_ < 15) { const float* p_ = xb + (c1_ + 1) * 96; xr0 = p_[0]; xr1 = p_[1]; xr2 = p_[2]; } \
    } \
} while(0)

    if (wv < 8) {
        // ========== L1 waves: lane owns units u = 16*lg + 2*wq + {0,1} ==========
        const int wq = wv;
        const int ga = col & 3;
        const float sca = (ga == 2) ? P2L2E : NL2E;
        bf16x8 Wf[2][3];
        f32x4 bia4[2];
#pragma unroll
        for (int tt = 0; tt < 2; ++tt) {
            const int n = ga * 64 + 16 * (col >> 2) + 2 * wq + tt;
#pragma unroll
            for (int f = 0; f < 3; ++f)
#pragma unroll
                for (int i = 0; i < 8; ++i) {
                    const int k = f * 32 + lg * 8 + i;
                    float v = 0.f;
                    if (k < 64)      v = Whh0[n * 64 + k];
                    else if (k < 67) v = Wih0[n * 3 + (k - 64)];
                    Wf[tt][f][i] = (short)f2bf(sca * v);
                }
#pragma unroll
            for (int r = 0; r < 4; ++r) {
                const int nb = r * 64 + 16 * lg + 2 * wq + tt;
                bia4[tt][r] = ((r == 2) ? P2L2E : NL2E) * (bih0[nb] + bhh0[nb]);
            }
        }
        const int hw = (col * 128 + 32 * lg + 4 * wq) ^ sw;
        f32x2 C01 = {0.f, 0.f};

#define L1B(RI, WI, S) do { \
        const char* rb_ = (const char*)ring[RI]; \
        bf16x8 v0_ = *(const bf16x8*)(rb_ + rd0); \
        bf16x8 v1_ = *(const bf16x8*)(rb_ + rd1); \
        bf16x8 v2_ = {0,0,0,0,0,0,0,0}; \
        if (lg == 0) \
            v2_ = *(const bf16x8*)((const char*)xq + ((((S)&63)) << 8) + ((col << 4) ^ (((S)&7) << 4))); \
        f32x4 a0_ = __builtin_amdgcn_mfma_f32_16x16x32_bf16(Wf[0][0], v0_, bia4[0],0,0,0); \
        f32x4 a1_ = __builtin_amdgcn_mfma_f32_16x16x32_bf16(Wf[1][0], v0_, bia4[1],0,0,0); \
        a0_ = __builtin_amdgcn_mfma_f32_16x16x32_bf16(Wf[0][1], v1_, a0_,0,0,0); \
        a1_ = __builtin_amdgcn_mfma_f32_16x16x32_bf16(Wf[1][1], v1_, a1_,0,0,0); \
        a0_ = __builtin_amdgcn_mfma_f32_16x16x32_bf16(Wf[0][2], v2_, a0_,0,0,0); \
        a1_ = __builtin_amdgcn_mfma_f32_16x16x32_bf16(Wf[1][2], v2_, a1_,0,0,0); \
        f32x2 h01_ = cellupd2(a0_, a1_, C01); \
        unsigned int p0_; \
        asm("v_cvt_pk_bf16_f32 %0, %1, %2" : "=v"(p0_) : "v"(h01_.x), "v"(h01_.y)); \
        *(unsigned int*)((char*)ring[WI] + hw) = p0_; \
    } while(0)

        L1B(1, 0, 0);
        __syncthreads();                           // end slot 0
#pragma unroll 1
        for (int m = 0; m < 255; ++m) {
            const int s1 = 2 * m + 1;
            L1B(0, 1, s1);
            __syncthreads();                       // end odd slot
            L1B(1, 0, s1 + 1);
            FLUSH(s1 + 1);
            __syncthreads();                       // end even slot
        }
        L1B(0, 1, 511);
        __syncthreads();                           // end slot 511
        __syncthreads();                           // slot 512 idle
#undef L1B
    } else {
        // ========== L2 waves: lag 1; K = [h1(64) | h2(64)]; units 16*lg+2*wq+{0,1} ==========
        const int wq = wv - 8;
        const int ga = col & 3;
        const float sca = (ga == 2) ? P2L2E : NL2E;
        bf16x8 Wf[2][4];
        f32x4 bia4[2];
#pragma unroll
        for (int tt = 0; tt < 2; ++tt) {
            const int n = ga * 64 + 16 * (col >> 2) + 2 * wq + tt;
#pragma unroll
            for (int f = 0; f < 4; ++f)
#pragma unroll
                for (int i = 0; i < 8; ++i) {
                    const int k = f * 32 + lg * 8 + i;
                    const float v = (k < 64) ? Wih1[n * 64 + k] : Whh1[n * 64 + (k - 64)];
                    Wf[tt][f][i] = (short)f2bf(sca * v);
                }
#pragma unroll
            for (int r = 0; r < 4; ++r) {
                const int nb = r * 64 + 16 * lg + 2 * wq + tt;
                bia4[tt][r] = ((r == 2) ? P2L2E : NL2E) * (bih1[nb] + bhh1[nb]);
            }
        }
        const int hw2 = (col * 128 + 32 * lg + 4 * wq) ^ sw;
        f32x2 C01 = {0.f, 0.f};
        f32x2 hv01 = {0.f, 0.f};

#define L2B(RB, HR) do { \
        const char* rb_ = (const char*)ring[RB]; \
        const char* hp_ = (const char*)h2s[HR]; \
        bf16x8 v0_ = *(const bf16x8*)(rb_ + rd0); \
        bf16x8 v1_ = *(const bf16x8*)(rb_ + rd1); \
        bf16x8 v2_ = *(const bf16x8*)(hp_ + rd0); \
        bf16x8 v3_ = *(const bf16x8*)(hp_ + rd1); \
        f32x4 a0_ = __builtin_amdgcn_mfma_f32_16x16x32_bf16(Wf[0][0], v0_, bia4[0],0,0,0); \
        f32x4 a1_ = __builtin_amdgcn_mfma_f32_16x16x32_bf16(Wf[1][0], v0_, bia4[1],0,0,0); \
        a0_ = __builtin_amdgcn_mfma_f32_16x16x32_bf16(Wf[0][1], v1_, a0_,0,0,0); \
        a1_ = __builtin_amdgcn_mfma_f32_16x16x32_bf16(Wf[1][1], v1_, a1_,0,0,0); \
        a0_ = __builtin_amdgcn_mfma_f32_16x16x32_bf16(Wf[0][2], v2_, a0_,0,0,0); \
        a1_ = __builtin_amdgcn_mfma_f32_16x16x32_bf16(Wf[1][2], v2_, a1_,0,0,0); \
        a0_ = __builtin_amdgcn_mfma_f32_16x16x32_bf16(Wf[0][3], v3_, a0_,0,0,0); \
        a1_ = __builtin_amdgcn_mfma_f32_16x16x32_bf16(Wf[1][3], v3_, a1_,0,0,0); \
        hv01 = cellupd2(a0_, a1_, C01); \
        unsigned int p0_; \
        asm("v_cvt_pk_bf16_f32 %0, %1, %2" : "=v"(p0_) : "v"(hv01.x), "v"(hv01.y)); \
        *(unsigned int*)((char*)h2s[RB] + hw2) = p0_; \
    } while(0)

        __syncthreads();                           // slot 0 idle
#pragma unroll 1
        for (int m = 0; m < 255; ++m) {
            L2B(0, 1);                             // slot 2m+1, t=2m
            __syncthreads();
            L2B(1, 0);                             // slot 2m+2, t=2m+1
            __syncthreads();
        }
        L2B(0, 1);                                 // slot 511, t=510
        __syncthreads();
        L2B(1, 0);                                 // slot 512, t=511
        __syncthreads();
#undef L2B
        const int ub = 16 * lg + 2 * wq;
        h2f[col][ub + 0] = hv01.x;
        h2f[col][ub + 1] = hv01.y;
    }
    __syncthreads();

    // ================= classifier head =================
    if (tid < 512) {
        const int b = tid & 15, j = tid >> 4;      // j 0..31
        float s = bc1[j];
#pragma unroll 8
        for (int k = 0; k < 64; ++k) s += Wc1[j * 64 + k] * h2f[b][k];
        hid[b][j] = fmaxf(s, 0.f);
    }
    __syncthreads();
    if (tid < 16) {
        float s = bc2[0];
#pragma unroll 8
        for (int k = 0; k < 32; ++k) s += Wc2[k] * hid[tid][k];
        float e = __builtin_amdgcn_exp2f(NL2E * s);
        out[b0 + tid] = __builtin_amdgcn_rcpf(1.f + e);
    }
}

extern "C" void kernel_launch(void* const* d_in, const int* in_sizes, int n_in,
                              void* d_out, int out_size, void* d_ws, size_t ws_size,
                              hipStream_t stream) {
    lstm2_kernel<<<BATCH / MROWS, 1024, 0, stream>>>(
        (const float*)d_in[0],
        (const float*)d_in[1], (const float*)d_in[2],
        (const float*)d_in[3], (const float*)d_in[4],
        (const float*)d_in[5], (const float*)d_in[6],
        (const float*)d_in[7], (const float*)d_in[8],
        (const float*)d_in[9], (const float*)d_in[10],
        (const float*)d_in[11], (const float*)d_in[12],
        (float*)d_out);
}